// Round 10
// baseline (382.885 us; speedup 1.0000x reference)
//
#include <hip/hip_runtime.h>
#include <stdint.h>

typedef unsigned short u16;
typedef __attribute__((ext_vector_type(8))) short short8;   // 8 bf16 = 4 VGPRs (MFMA A/B frag)
typedef __attribute__((ext_vector_type(4))) float f32x4;    // MFMA C/D frag

#define LOG2E 1.4426950408889634f
#define NT 8192
#define DH 256

// ---- workspace layout (u16 element offsets) ----
// persistent across flash:
#define QH     0
#define KH     2097152
#define VTB    4194304          // V transposed: [256][8192]
#define OPARTB 6291456          // 8 x [8192][256] bf16 unnormalized partial O (32 MB)
// temps (dead after k_qkv; deliberately overlap OPARTB region):
#define XH0 6291456
#define XL0 8388608
#define XH1 10485760
#define XL1 12582912
#define XH2 14680064
#define XL2 16777216
#define WQH 18874368
#define WQL 18939904
#define WKH 19005440
#define WKL 19070976
#define WVH 19136512
#define WVL 19202048
// fp32 region (float element offsets), after OPARTB (byte 46,137,344):
#define MPART_F 11534336        // 8 x [8192] per-split softmax base m0
#define LPART_F 11599872        // 8 x [8192] per-split denom

__device__ __forceinline__ u16 f2bf(float f) {
  union { float f; uint32_t u; } c; c.f = f;
  uint32_t u = c.u;
  return (u16)((u + 0x7fffu + ((u >> 16) & 1)) >> 16);   // RNE
}
__device__ __forceinline__ u16 f2bf_hu(float f) {        // round-half-up: 2 VALU ops
  union { float f; uint32_t u; } c; c.f = f;
  return (u16)((c.u + 0x8000u) >> 16);
}
__device__ __forceinline__ float bf2f(u16 h) {
  union { uint32_t u; float f; } c; c.u = ((uint32_t)h) << 16;
  return c.f;
}

// XOR swizzle for LDS rows of 32 16B-units (512B rows)
__device__ __forceinline__ int swz32(int u, int row) {
  return (u & 24) | ((u & 7) ^ (row & 7));
}

__device__ __forceinline__ f32x4 mfma16(short8 a, short8 b, f32x4 c) {
  return __builtin_amdgcn_mfma_f32_16x16x32_bf16(a, b, c, 0, 0, 0);
}

// ---------------- kernel 1: fp32 -> hi/lo bf16 split ----------------
__global__ __launch_bounds__(256) void k_convert(
    const float* __restrict__ x1, const float* __restrict__ x2, const float* __restrict__ x3,
    const float* __restrict__ wq, const float* __restrict__ wk, const float* __restrict__ wv,
    u16* __restrict__ wsu) {
  int b = blockIdx.x;
  const float* src; u16 *dh, *dl; int bl;
  if (b < 1024)      { src = x1; dh = wsu + XH0; dl = wsu + XL0; bl = b; }
  else if (b < 2048) { src = x2; dh = wsu + XH1; dl = wsu + XL1; bl = b - 1024; }
  else if (b < 3072) { src = x3; dh = wsu + XH2; dl = wsu + XL2; bl = b - 2048; }
  else if (b < 3104) { src = wq; dh = wsu + WQH; dl = wsu + WQL; bl = b - 3072; }
  else if (b < 3136) { src = wk; dh = wsu + WKH; dl = wsu + WKL; bl = b - 3104; }
  else               { src = wv; dh = wsu + WVH; dl = wsu + WVL; bl = b - 3136; }
  int i = (bl * 256 + threadIdx.x) * 8;
  f32x4 a = *(const f32x4*)(src + i);
  f32x4 c = *(const f32x4*)(src + i + 4);
  short8 rh, rl;
  float v[8] = {a[0], a[1], a[2], a[3], c[0], c[1], c[2], c[3]};
#pragma unroll
  for (int j = 0; j < 8; j++) {
    u16 h = f2bf(v[j]);
    rh[j] = (short)h;
    rl[j] = (short)f2bf(v[j] - bf2f(h));
  }
  *(short8*)(dh + i) = rh;
  *(short8*)(dl + i) = rl;
}

// ---------------- kernel 2: QKV projection v3 — A-stationary (unchanged from R9) ----------------
__global__ __launch_bounds__(256) void k_qkv(
    u16* __restrict__ wsu,
    const float* __restrict__ bq, const float* __restrict__ bk, const float* __restrict__ bv) {
  __shared__ u16 sAh[32 * 256];   // 16 KB
  __shared__ u16 sAl[32 * 256];   // 16 KB
  int bx = blockIdx.x;
  int mid = bx >> 8;
  int t = bx & 255;
  const u16 *Ah, *Al, *Bh, *Bl; u16 *O; const float* bias;
  int rowA0, col0, ldO, biasRow;
  if (mid == 0) {
    Ah = wsu + XH0; Al = wsu + XL0; Bh = wsu + WQH; Bl = wsu + WQL;
    O = wsu + QH; bias = bq; biasRow = 0; ldO = 256;
    rowA0 = t * 32; col0 = 0;
  } else if (mid == 1) {
    Ah = wsu + XH1; Al = wsu + XL1; Bh = wsu + WKH; Bl = wsu + WKL;
    O = wsu + KH; bias = bk; biasRow = 0; ldO = 256;
    rowA0 = t * 32; col0 = 0;
  } else {
    Ah = wsu + WVH; Al = wsu + WVL; Bh = wsu + XH2; Bl = wsu + XL2;
    O = wsu + VTB; bias = bv; biasRow = 1; ldO = 8192;
    rowA0 = (t & 7) * 32; col0 = (t >> 3) * 256;
  }

  int tid = threadIdx.x;
#pragma unroll
  for (int i = 0; i < 4; i++) {            // stage A hi/lo: 32 rows x 32 units each
    int L = i * 256 + tid;
    int row = L >> 5, u = L & 31;
    short8 vh = *(const short8*)(Ah + (size_t)(rowA0 + row) * 256 + u * 8);
    short8 vl = *(const short8*)(Al + (size_t)(rowA0 + row) * 256 + u * 8);
    *(short8*)(&sAh[row * 256 + swz32(u, row) * 8]) = vh;
    *(short8*)(&sAl[row * 256 + swz32(u, row) * 8]) = vl;
  }
  __syncthreads();

  int lane = tid & 63, wave = tid >> 6;
  int n = lane & 15, quad = lane >> 4;

#pragma unroll 1
  for (int itc = 0; itc < 4; itc++) {
    int colg = col0 + itc * 64 + wave * 16 + n;
    const u16* pBh = Bh + (size_t)colg * 256 + quad * 8;
    const u16* pBl = Bl + (size_t)colg * 256 + quad * 8;
    f32x4 acc0 = {0.f,0.f,0.f,0.f}, acc1 = {0.f,0.f,0.f,0.f};
#pragma unroll
    for (int kk = 0; kk < 8; kk++) {
      int su = swz32(kk * 4 + quad, n) * 8;     // n and n+16 share (row&7) -> same su
      short8 a0h = *(const short8*)(&sAh[n * 256 + su]);
      short8 a1h = *(const short8*)(&sAh[(n + 16) * 256 + su]);
      short8 a0l = *(const short8*)(&sAl[n * 256 + su]);
      short8 a1l = *(const short8*)(&sAl[(n + 16) * 256 + su]);
      short8 bh  = *(const short8*)(pBh + kk * 32);
      short8 bl  = *(const short8*)(pBl + kk * 32);
      acc0 = mfma16(a0h, bh, acc0);
      acc1 = mfma16(a1h, bh, acc1);
      acc0 = mfma16(a0h, bl, acc0);
      acc1 = mfma16(a1h, bl, acc1);
      acc0 = mfma16(a0l, bh, acc0);
      acc1 = mfma16(a1l, bh, acc1);
    }
    float bcol = biasRow ? 0.0f : bias[colg];
#pragma unroll
    for (int mt = 0; mt < 2; mt++) {
      f32x4 acc = mt ? acc1 : acc0;
#pragma unroll
      for (int r = 0; r < 4; r++) {
        int rowg = rowA0 + mt * 16 + quad * 4 + r;
        float bb = biasRow ? bias[rowg] : bcol;
        O[(size_t)rowg * ldO + colg] = f2bf(acc[r] + bb);
      }
    }
  }
}

// ---------------- kernel 3: flash attention v6 — barrier-free, K/V direct from L2 ----------------
// grid: 512 = 64 q-blocks x 8 key-splits; 4 waves x 32 q-rows. K/V MFMA B-fragments are
// contiguous 16B global loads (L2-resident per XCD via split pinning): no LDS staging, no
// barriers, no DMA. LDS only holds the private per-wave P tile (C->A transform).
// Even keys -> s*0 tiles, odd keys -> s*1 (addressing-only change) so each lane's two
// P values are k-adjacent -> packed b32 P-writes.
// Address discipline: uniform bases recomputed per iter (scalar), loop-invariant lane
// offsets, small immediates. NO persistent per-lane pointer arrays (R6/R7 spill lesson).
__global__ __launch_bounds__(256, 2) void k_flash(
    const u16* __restrict__ wsu, u16* __restrict__ opart, float* __restrict__ wsf) {
  __shared__ u16 sP[4 * 32 * 40];    // 10 KB: per-wave 32x32 P, stride 40

  int qb = blockIdx.x >> 3, sp = blockIdx.x & 7;   // split -> XCD pinning (512KB K + 512KB V per XCD L2)
  int tid = threadIdx.x, lane = tid & 63, wave = tid >> 6;
  int n = lane & 15, quad = lane >> 4;
  const u16* Qp = wsu + QH;
  const u16* Kp = wsu + KH;
  const u16* Vp = wsu + VTB;

  // Q fragments (A-layout) for 2 m-tiles: 64 VGPR
  short8 qf[2][8];
  int rowQ0 = qb * 128 + wave * 32 + n;
#pragma unroll
  for (int mt = 0; mt < 2; mt++)
#pragma unroll
    for (int kk = 0; kk < 8; kk++)
      qf[mt][kk] = *(const short8*)(Qp + (size_t)(rowQ0 + mt * 16) * 256 + kk * 32 + quad * 8);

  f32x4 o[2][16];
#pragma unroll
  for (int mt = 0; mt < 2; mt++)
#pragma unroll
    for (int nt = 0; nt < 16; nt++) { o[mt][nt][0]=0.f; o[mt][nt][1]=0.f; o[mt][nt][2]=0.f; o[mt][nt][3]=0.f; }
  float negm0L[8], lcur[8];
#pragma unroll
  for (int j = 0; j < 8; j++) { negm0L[j] = 0.f; lcur[j] = 0.f; }

  // loop-invariant lane offsets (u16 elements)
  int koff = n * 512 + quad * 8;       // key row 2n (even): (2n)*256 + quad*8; odd pair = +256
  int voff = n * 8192 + quad * 8;      // V^T row d=n (within nt group), col quad*8
  u16* myP = &sP[wave * 1280];

  for (int it = 0; it < 32; it++) {
    int key0 = sp * 1024 + it * 32;                   // uniform
    const u16* kb = Kp + (size_t)key0 * 256;          // uniform base, advances 16 KB/iter
    const u16* vb = Vp + key0;                        // uniform base, advances 64 B/iter

    // S = Q K^T: 32 MFMA; B-frags direct from L2. s*0 = even keys (2n), s*1 = odd (2n+1).
    f32x4 s00={0.f,0.f,0.f,0.f}, s01={0.f,0.f,0.f,0.f};
    f32x4 s10={0.f,0.f,0.f,0.f}, s11={0.f,0.f,0.f,0.f};
#pragma unroll
    for (int kk = 0; kk < 8; kk++) {
      short8 b0 = *(const short8*)(kb + koff + kk * 32);          // imm: kk*64 B
      short8 b1 = *(const short8*)(kb + koff + 256 + kk * 32);    // imm: 512 + kk*64 B
      s00 = mfma16(qf[0][kk], b0, s00);
      s01 = mfma16(qf[0][kk], b1, s01);
      s10 = mfma16(qf[1][kk], b0, s10);
      s11 = mfma16(qf[1][kk], b1, s11);
    }

    // fixed softmax base from first tile (no online rescale; logits bounded)
    if (it == 0) {
#pragma unroll
      for (int mt = 0; mt < 2; mt++)
#pragma unroll
        for (int r = 0; r < 4; r++) {
          float v = mt ? fmaxf(s10[r], s11[r]) : fmaxf(s00[r], s01[r]);
          v = fmaxf(v, __shfl_xor(v, 1));
          v = fmaxf(v, __shfl_xor(v, 2));
          v = fmaxf(v, __shfl_xor(v, 4));
          v = fmaxf(v, __shfl_xor(v, 8));
          negm0L[mt * 4 + r] = -v * LOG2E;
        }
    }

    // p = exp2(s*log2e + negm0); accumulate l; pack adjacent (even,odd) pair as one b32 write
#pragma unroll
    for (int mt = 0; mt < 2; mt++)
#pragma unroll
      for (int r = 0; r < 4; r++) {
        int j = mt * 4 + r;
        float sv0 = mt ? s10[r] : s00[r];    // key 2n
        float sv1 = mt ? s11[r] : s01[r];    // key 2n+1
        float p0 = exp2f(fmaf(sv0, LOG2E, negm0L[j]));
        float p1 = exp2f(fmaf(sv1, LOG2E, negm0L[j]));
        lcur[j] += p0 + p1;
        int row = mt * 16 + quad * 4 + r;
        uint32_t pk = (uint32_t)f2bf_hu(p0) | ((uint32_t)f2bf_hu(p1) << 16);
        *(uint32_t*)&myP[row * 40 + 2 * n] = pk;     // byte addr row*80+4n: 4-aligned
      }

    // PV: O[32 x 256] += P[32 x 32] @ V[32 x 256]; V B-frags direct from L2
    short8 pa0 = *(const short8*)(&myP[n * 40 + quad * 8]);
    short8 pa1 = *(const short8*)(&myP[(16 + n) * 40 + quad * 8]);
#pragma unroll
    for (int nt = 0; nt < 16; nt++) {
      short8 vbf = *(const short8*)(vb + (size_t)nt * 131072 + voff);  // nt*16*8192 uniform
      o[0][nt] = mfma16(pa0, vbf, o[0][nt]);
      o[1][nt] = mfma16(pa1, vbf, o[1][nt]);
    }
  }

  // reduce l across the 16 lanes sharing rows
#pragma unroll
  for (int j = 0; j < 8; j++) {
    float v = lcur[j];
    v += __shfl_xor(v, 1); v += __shfl_xor(v, 2);
    v += __shfl_xor(v, 4); v += __shfl_xor(v, 8);
    lcur[j] = v;
  }

  // store bf16 unnormalized partials + stats
  u16* op = opart + (size_t)sp * (NT * DH);
  int rowb = qb * 128 + wave * 32;
#pragma unroll
  for (int mt = 0; mt < 2; mt++)
#pragma unroll
    for (int nt = 0; nt < 16; nt++)
#pragma unroll
      for (int r = 0; r < 4; r++) {
        int row = rowb + mt * 16 + quad * 4 + r;
        op[(size_t)row * 256 + nt * 16 + n] = f2bf(o[mt][nt][r]);
      }
  if (n == 0) {
#pragma unroll
    for (int j = 0; j < 8; j++) {
      int row = rowb + (j >> 2) * 16 + quad * 4 + (j & 3);
      wsf[MPART_F + sp * NT + row] = negm0L[j] * -0.6931471805599453f;
      wsf[LPART_F + sp * NT + row] = lcur[j];
    }
  }
}

// ---------------- kernel 4: combine 8 splits ----------------
__global__ __launch_bounds__(256) void k_combine(
    const u16* __restrict__ opart, const float* __restrict__ wsf, float* __restrict__ out) {
  int gid = blockIdx.x * 256 + threadIdx.x;
  int row = gid >> 6, cg = gid & 63;
  float m[8], l[8];
#pragma unroll
  for (int s = 0; s < 8; s++) {
    m[s] = wsf[MPART_F + s * NT + row];
    l[s] = wsf[LPART_F + s * NT + row];
  }
  float ms = m[0];
#pragma unroll
  for (int s = 1; s < 8; s++) ms = fmaxf(ms, m[s]);
  float denom = 0.f;
  float acc[4] = {0.f, 0.f, 0.f, 0.f};
#pragma unroll
  for (int s = 0; s < 8; s++) {
    float w = exp2f((m[s] - ms) * LOG2E);
    denom += w * l[s];
    const u16* pp = opart + ((size_t)s * NT + row) * 256 + cg * 4;
    uint2 v = *(const uint2*)pp;
    acc[0] += w * bf2f((u16)(v.x & 0xffff));
    acc[1] += w * bf2f((u16)(v.x >> 16));
    acc[2] += w * bf2f((u16)(v.y & 0xffff));
    acc[3] += w * bf2f((u16)(v.y >> 16));
  }
  float inv = 1.0f / denom;
  f32x4 r = {acc[0] * inv, acc[1] * inv, acc[2] * inv, acc[3] * inv};
  *(f32x4*)(out + (size_t)row * 256 + cg * 4) = r;
}

extern "C" void kernel_launch(void* const* d_in, const int* in_sizes, int n_in,
                              void* d_out, int out_size, void* d_ws, size_t ws_size,
                              hipStream_t stream) {
  const float* x1 = (const float*)d_in[0];
  const float* x2 = (const float*)d_in[1];
  const float* x3 = (const float*)d_in[2];
  const float* Wq = (const float*)d_in[3];
  const float* bq = (const float*)d_in[4];
  const float* Wk = (const float*)d_in[5];
  const float* bk = (const float*)d_in[6];
  const float* Wv = (const float*)d_in[7];
  const float* bv = (const float*)d_in[8];
  u16* wsu = (u16*)d_ws;
  float* wsf = (float*)d_ws;
  float* out = (float*)d_out;

  k_convert<<<dim3(3168), dim3(256), 0, stream>>>(x1, x2, x3, Wq, Wk, Wv, wsu);
  k_qkv<<<dim3(768), dim3(256), 0, stream>>>(wsu, bq, bk, bv);
  k_flash<<<dim3(512), dim3(256), 0, stream>>>(wsu, wsu + OPARTB, wsf);
  k_combine<<<dim3(2048), dim3(256), 0, stream>>>(wsu + OPARTB, wsf, out);
}

// Round 11
// 217.588 us; speedup vs baseline: 1.7597x; 1.7597x over previous
//
#include <hip/hip_runtime.h>
#include <stdint.h>

typedef unsigned short u16;
typedef __attribute__((ext_vector_type(8))) short short8;   // 8 bf16 = 4 VGPRs (MFMA A/B frag)
typedef __attribute__((ext_vector_type(4))) float f32x4;    // MFMA C/D frag

#define LOG2E 1.4426950408889634f
#define NT 8192
#define DH 256

// ---- workspace layout (u16 element offsets) ----
#define QH     0
#define KH     2097152
#define VTB    4194304          // V transposed: [256][8192]
#define OPARTB 6291456          // 8 x [8192][256] bf16 unnormalized partial O (32 MB)
// temps (dead after k_qkv; deliberately overlap OPARTB region):
#define XH0 6291456
#define XL0 8388608
#define XH1 10485760
#define XL1 12582912
#define XH2 14680064
#define XL2 16777216
#define WQH 18874368
#define WQL 18939904
#define WKH 19005440
#define WKL 19070976
#define WVH 19136512
#define WVL 19202048
// fp32 region (float element offsets), after OPARTB:
#define MPART_F 11534336        // 8 x [8192] per-split softmax base m0
#define LPART_F 11599872        // 8 x [8192] per-split denom

__device__ __forceinline__ u16 f2bf(float f) {
  union { float f; uint32_t u; } c; c.f = f;
  uint32_t u = c.u;
  return (u16)((u + 0x7fffu + ((u >> 16) & 1)) >> 16);   // RNE
}
__device__ __forceinline__ u16 f2bf_hu(float f) {        // round-half-up
  union { float f; uint32_t u; } c; c.f = f;
  return (u16)((c.u + 0x8000u) >> 16);
}
__device__ __forceinline__ float bf2f(u16 h) {
  union { uint32_t u; float f; } c; c.u = ((uint32_t)h) << 16;
  return c.f;
}

// XOR swizzle for LDS rows of 32 16B-units (512B rows)
__device__ __forceinline__ int swz32(int u, int h) {    // h = row hash (3 bits)
  return (u & 24) | ((u & 7) ^ (h & 7));
}

__device__ __forceinline__ f32x4 mfma16(short8 a, short8 b, f32x4 c) {
  return __builtin_amdgcn_mfma_f32_16x16x32_bf16(a, b, c, 0, 0, 0);
}

// async global->LDS, 16B per lane; LDS dest is wave-uniform base + lane*16
__device__ __forceinline__ void gl_lds16(const u16* g, u16* l) {
  __builtin_amdgcn_global_load_lds(
      (const __attribute__((address_space(1))) uint32_t*)g,
      (__attribute__((address_space(3))) uint32_t*)l, 16, 0, 0);
}

// ---------------- kernel 1: fp32 -> hi/lo bf16 split ----------------
__global__ __launch_bounds__(256) void k_convert(
    const float* __restrict__ x1, const float* __restrict__ x2, const float* __restrict__ x3,
    const float* __restrict__ wq, const float* __restrict__ wk, const float* __restrict__ wv,
    u16* __restrict__ wsu) {
  int b = blockIdx.x;
  const float* src; u16 *dh, *dl; int bl;
  if (b < 1024)      { src = x1; dh = wsu + XH0; dl = wsu + XL0; bl = b; }
  else if (b < 2048) { src = x2; dh = wsu + XH1; dl = wsu + XL1; bl = b - 1024; }
  else if (b < 3072) { src = x3; dh = wsu + XH2; dl = wsu + XL2; bl = b - 2048; }
  else if (b < 3104) { src = wq; dh = wsu + WQH; dl = wsu + WQL; bl = b - 3072; }
  else if (b < 3136) { src = wk; dh = wsu + WKH; dl = wsu + WKL; bl = b - 3104; }
  else               { src = wv; dh = wsu + WVH; dl = wsu + WVL; bl = b - 3136; }
  int i = (bl * 256 + threadIdx.x) * 8;
  f32x4 a = *(const f32x4*)(src + i);
  f32x4 c = *(const f32x4*)(src + i + 4);
  short8 rh, rl;
  float v[8] = {a[0], a[1], a[2], a[3], c[0], c[1], c[2], c[3]};
#pragma unroll
  for (int j = 0; j < 8; j++) {
    u16 h = f2bf(v[j]);
    rh[j] = (short)h;
    rl[j] = (short)f2bf(v[j] - bf2f(h));
  }
  *(short8*)(dh + i) = rh;
  *(short8*)(dl + i) = rl;
}

// ---------------- kernel 2: QKV projection v5 — A-stationary + DMA-staged B ----------------
// NT gemm, 3-term hi/lo. Block owns 32 A-rows (staged once, 32 KB) and sweeps 8 groups of
// 32 output cols; each group's B rows (hi+lo, 32 KB) staged via contiguous gl_lds16 DMA —
// no scattered global loads (R10 lesson: scattered per-lane 16B loads are TA/L2-toxic).
// LDS 64 KB -> 2 blocks/CU. MFMA term order identical to R9 -> bitwise-same Q/K/Vt.
__global__ __launch_bounds__(256) void k_qkv(
    u16* __restrict__ wsu,
    const float* __restrict__ bq, const float* __restrict__ bk, const float* __restrict__ bv) {
  __shared__ u16 sAh[32 * 256];   // 16 KB
  __shared__ u16 sAl[32 * 256];   // 16 KB
  __shared__ u16 sBh[32 * 256];   // 16 KB (current col-group, hi)
  __shared__ u16 sBl[32 * 256];   // 16 KB (lo)
  int bx = blockIdx.x;
  int mid = bx >> 8;
  int t = bx & 255;
  const u16 *Ah, *Al, *Bh, *Bl; u16 *O; const float* bias;
  int rowA0, colBase, ldO, biasRow;
  if (mid == 0) {
    Ah = wsu + XH0; Al = wsu + XL0; Bh = wsu + WQH; Bl = wsu + WQL;
    O = wsu + QH; bias = bq; biasRow = 0; ldO = 256;
    rowA0 = t * 32; colBase = 0;
  } else if (mid == 1) {
    Ah = wsu + XH1; Al = wsu + XL1; Bh = wsu + WKH; Bl = wsu + WKL;
    O = wsu + KH; bias = bk; biasRow = 0; ldO = 256;
    rowA0 = t * 32; colBase = 0;
  } else {
    Ah = wsu + WVH; Al = wsu + WVL; Bh = wsu + XH2; Bl = wsu + XL2;
    O = wsu + VTB; bias = bv; biasRow = 1; ldO = 8192;
    rowA0 = (t & 7) * 32; colBase = (t >> 3) * 256;
  }

  int tid = threadIdx.x;
  int lane = tid & 63, wave = tid >> 6;
  int n = lane & 15, quad = lane >> 4;
  int wm = wave >> 1, wn = wave & 1;

  // stage A once (plain contiguous loads)
#pragma unroll
  for (int i = 0; i < 4; i++) {
    int L = i * 256 + tid;
    int row = L >> 5, u = L & 31;
    short8 vh = *(const short8*)(Ah + (size_t)(rowA0 + row) * 256 + u * 8);
    short8 vl = *(const short8*)(Al + (size_t)(rowA0 + row) * 256 + u * 8);
    *(short8*)(&sAh[row * 256 + swz32(u, row) * 8]) = vh;
    *(short8*)(&sAl[row * 256 + swz32(u, row) * 8]) = vl;
  }

  // B DMA lane geometry: rows i*8 + brow0, dest unit p = lane&31, source unit inv-swizzled
  int brow0 = wave * 2 + (lane >> 5);
  int bgu = (lane & 24) | ((lane & 7) ^ (brow0 & 7));   // (i*8+brow0)&7 == brow0&7 (i-invariant)

  // issue DMA for group 0
#pragma unroll
  for (int i = 0; i < 4; i++) {
    gl_lds16(Bh + (size_t)(colBase + i * 8 + brow0) * 256 + bgu * 8, &sBh[i * 2048 + wave * 512]);
    gl_lds16(Bl + (size_t)(colBase + i * 8 + brow0) * 256 + bgu * 8, &sBl[i * 2048 + wave * 512]);
  }

#pragma unroll 1
  for (int g = 0; g < 8; g++) {
    __syncthreads();   // DMA for group g drained (vmcnt 0 at barrier) + A visible

    int colg = colBase + g * 32 + wn * 16 + n;
    f32x4 acc = {0.f, 0.f, 0.f, 0.f};
#pragma unroll
    for (int kk = 0; kk < 8; kk++) {
      int ra = wm * 16 + n;
      int rbB = wn * 16 + n;
      short8 ah = *(const short8*)(&sAh[ra * 256 + swz32(kk * 4 + quad, ra) * 8]);
      short8 al = *(const short8*)(&sAl[ra * 256 + swz32(kk * 4 + quad, ra) * 8]);
      short8 bh = *(const short8*)(&sBh[rbB * 256 + swz32(kk * 4 + quad, rbB) * 8]);
      short8 bl = *(const short8*)(&sBl[rbB * 256 + swz32(kk * 4 + quad, rbB) * 8]);
      acc = mfma16(ah, bh, acc);
      acc = mfma16(ah, bl, acc);
      acc = mfma16(al, bh, acc);
    }

    if (g < 7) {
      __syncthreads();   // all waves done reading group g's B
      int b0 = colBase + (g + 1) * 32;
#pragma unroll
      for (int i = 0; i < 4; i++) {
        gl_lds16(Bh + (size_t)(b0 + i * 8 + brow0) * 256 + bgu * 8, &sBh[i * 2048 + wave * 512]);
        gl_lds16(Bl + (size_t)(b0 + i * 8 + brow0) * 256 + bgu * 8, &sBl[i * 2048 + wave * 512]);
      }
    }

    float bcol = biasRow ? 0.0f : bias[colg];
#pragma unroll
    for (int r = 0; r < 4; r++) {
      int rowg = rowA0 + wm * 16 + quad * 4 + r;
      float bb = biasRow ? bias[rowg] : bcol;
      O[(size_t)rowg * ldO + colg] = f2bf(acc[r] + bb);
    }
  }
}

// ---------------- kernel 3: flash attention v7 (R4 structure + packed P writes) ----------------
// grid: 512 = 64 q-blocks x 8 key-splits; 4 waves x 32 q-rows each. Double-buffered K/V via
// gl_lds16, one barrier/iter, fixed-base softmax. sK row hash = (row>>1)&7 so the two S
// n-tiles are even/odd keys: b1 = b0 + 512B immediate, and each lane's two P values are
// k-adjacent -> single b32 LDS write (halves P-write issue cost on the LDS pipe).
// NO persistent per-lane pointer arrays (R6/R7 spill lesson); K/V stay LDS-staged (R10 lesson).
__global__ __launch_bounds__(256, 2) void k_flash(
    const u16* __restrict__ wsu, u16* __restrict__ opart, float* __restrict__ wsf) {
  __shared__ u16 sK[2][32 * 256];    // 2 x 16 KB, hash=(row>>1)&7
  __shared__ u16 sV[2][256 * 32];    // 2 x 16 KB
  __shared__ u16 sP[4 * 32 * 40];    // 10 KB: per-wave 32x32 P, stride 40

  int qb = blockIdx.x >> 3, sp = blockIdx.x & 7;   // split -> XCD pinning
  int tid = threadIdx.x, lane = tid & 63, wave = tid >> 6;
  int n = lane & 15, quad = lane >> 4;
  const u16* Qp = wsu + QH;
  const u16* Kp = wsu + KH;
  const u16* Vp = wsu + VTB;

  // Q fragments (A-layout) for 2 m-tiles: 64 VGPR
  short8 qf[2][8];
  int rowQ0 = qb * 128 + wave * 32 + n;
#pragma unroll
  for (int mt = 0; mt < 2; mt++)
#pragma unroll
    for (int kk = 0; kk < 8; kk++)
      qf[mt][kk] = *(const short8*)(Qp + (size_t)(rowQ0 + mt * 16) * 256 + kk * 32 + quad * 8);

  // staging lane geometry. K rows per call: i*8 + krow0; hash=((i*8+krow0)>>1)&7 =
  // (i*4 + (krow0>>1))&7 -> for i even it's kh0, i odd it's kh0^4 (krow0>>1 in 0..3).
  int krow0 = wave * 2 + (lane >> 5);
  int kh0 = (krow0 >> 1) & 7;
  int kgu0 = (lane & 24) | ((lane & 7) ^ kh0);            // units for i = 0, 2
  int kgu1 = kgu0 ^ 4;                                    // units for i = 1, 3
  int vd_base = wave * 16 + (lane >> 2);                  // V d = i*64 + vd_base
  int vgu = (lane & 3) ^ ((lane >> 3) & 3);

  int key00 = sp * 1024;

  // preload tile 0 into buffer 0
#pragma unroll
  for (int i = 0; i < 4; i++) {
    int ku = (i & 1) ? kgu1 : kgu0;
    gl_lds16(Kp + (size_t)(key00 + i * 8 + krow0) * 256 + ku * 8,
             &sK[0][i * 2048 + wave * 512]);
    gl_lds16(Vp + (size_t)(i * 64 + vd_base) * 8192 + key00 + vgu * 8,
             &sV[0][i * 2048 + wave * 512]);
  }

  f32x4 o[2][16];
#pragma unroll
  for (int mt = 0; mt < 2; mt++)
#pragma unroll
    for (int nt = 0; nt < 16; nt++) { o[mt][nt][0]=0.f; o[mt][nt][1]=0.f; o[mt][nt][2]=0.f; o[mt][nt][3]=0.f; }
  float negm0L[8], lcur[8];
#pragma unroll
  for (int j = 0; j < 8; j++) { negm0L[j] = 0.f; lcur[j] = 0.f; }

  for (int it = 0; it < 32; it++) {
    __syncthreads();   // buf[cur] DMA complete; all waves done with buf[cur^1]
    int cur = it & 1;
    if (it + 1 < 32) {
      int k1 = key00 + (it + 1) * 32;
#pragma unroll
      for (int i = 0; i < 4; i++) {
        int ku = (i & 1) ? kgu1 : kgu0;
        gl_lds16(Kp + (size_t)(k1 + i * 8 + krow0) * 256 + ku * 8,
                 &sK[cur ^ 1][i * 2048 + wave * 512]);
        gl_lds16(Vp + (size_t)(i * 64 + vd_base) * 8192 + k1 + vgu * 8,
                 &sV[cur ^ 1][i * 2048 + wave * 512]);
      }
    }

    // S = Q K^T: s*0 = even keys (2n), s*1 = odd keys (2n+1); hash(2n)=hash(2n+1)=n&7
    // -> same swizzled unit, b1 = b0 + 512B immediate.
    f32x4 s00={0.f,0.f,0.f,0.f}, s01={0.f,0.f,0.f,0.f};
    f32x4 s10={0.f,0.f,0.f,0.f}, s11={0.f,0.f,0.f,0.f};
#pragma unroll
    for (int kk = 0; kk < 8; kk++) {
      int su = swz32(kk * 4 + quad, n) * 8;
      short8 b0 = *(const short8*)(&sK[cur][(2 * n) * 256 + su]);
      short8 b1 = *(const short8*)(&sK[cur][(2 * n) * 256 + 256 + su]);
      s00 = mfma16(qf[0][kk], b0, s00);
      s01 = mfma16(qf[0][kk], b1, s01);
      s10 = mfma16(qf[1][kk], b0, s10);
      s11 = mfma16(qf[1][kk], b1, s11);
    }

    // fixed softmax base from first tile (covers even+odd = all keys)
    if (it == 0) {
#pragma unroll
      for (int mt = 0; mt < 2; mt++)
#pragma unroll
        for (int r = 0; r < 4; r++) {
          float v = mt ? fmaxf(s10[r], s11[r]) : fmaxf(s00[r], s01[r]);
          v = fmaxf(v, __shfl_xor(v, 1));
          v = fmaxf(v, __shfl_xor(v, 2));
          v = fmaxf(v, __shfl_xor(v, 4));
          v = fmaxf(v, __shfl_xor(v, 8));
          negm0L[mt * 4 + r] = -v * LOG2E;
        }
    }

    // p = exp2(s*log2e + negm0); pack (key 2n, key 2n+1) as one b32 LDS write
    u16* myP = &sP[wave * 1280];
#pragma unroll
    for (int mt = 0; mt < 2; mt++)
#pragma unroll
      for (int r = 0; r < 4; r++) {
        int j = mt * 4 + r;
        float sv0 = mt ? s10[r] : s00[r];
        float sv1 = mt ? s11[r] : s01[r];
        float x0 = fminf(fmaf(sv0, LOG2E, negm0L[j]), 110.f);
        float x1 = fminf(fmaf(sv1, LOG2E, negm0L[j]), 110.f);
        float p0 = exp2f(x0);
        float p1 = exp2f(x1);
        lcur[j] += p0 + p1;
        int row = mt * 16 + quad * 4 + r;
        uint32_t pk = (uint32_t)f2bf_hu(p0) | ((uint32_t)f2bf_hu(p1) << 16);
        *(uint32_t*)&myP[row * 40 + 2 * n] = pk;   // byte row*80+4n, 4-aligned, banks n -> conflict-free
      }

    // PV: O[32 x 256] += P[32 x 32] @ V[32 x 256]
    short8 pa0 = *(const short8*)(&myP[n * 40 + quad * 8]);
    short8 pa1 = *(const short8*)(&myP[(16 + n) * 40 + quad * 8]);
#pragma unroll
    for (int nt = 0; nt < 16; nt++) {
      int d = nt * 16 + n;
      short8 vb = *(const short8*)(&sV[cur][d * 32 + (quad ^ ((n >> 1) & 3)) * 8]);
      o[0][nt] = mfma16(pa0, vb, o[0][nt]);
      o[1][nt] = mfma16(pa1, vb, o[1][nt]);
    }
  }

  // reduce l across the 16 lanes sharing rows
#pragma unroll
  for (int j = 0; j < 8; j++) {
    float v = lcur[j];
    v += __shfl_xor(v, 1); v += __shfl_xor(v, 2);
    v += __shfl_xor(v, 4); v += __shfl_xor(v, 8);
    lcur[j] = v;
  }

  // store bf16 unnormalized partials + stats
  u16* op = opart + (size_t)sp * (NT * DH);
  int rowb = qb * 128 + wave * 32;
#pragma unroll
  for (int mt = 0; mt < 2; mt++)
#pragma unroll
    for (int nt = 0; nt < 16; nt++)
#pragma unroll
      for (int r = 0; r < 4; r++) {
        int row = rowb + mt * 16 + quad * 4 + r;
        op[(size_t)row * 256 + nt * 16 + n] = f2bf(o[mt][nt][r]);
      }
  if (n == 0) {
#pragma unroll
    for (int j = 0; j < 8; j++) {
      int row = rowb + (j >> 2) * 16 + quad * 4 + (j & 3);
      wsf[MPART_F + sp * NT + row] = negm0L[j] * -0.6931471805599453f;
      wsf[LPART_F + sp * NT + row] = lcur[j];
    }
  }
}

// ---------------- kernel 4: combine 8 splits ----------------
__global__ __launch_bounds__(256) void k_combine(
    const u16* __restrict__ opart, const float* __restrict__ wsf, float* __restrict__ out) {
  int gid = blockIdx.x * 256 + threadIdx.x;
  int row = gid >> 6, cg = gid & 63;
  float m[8], l[8];
#pragma unroll
  for (int s = 0; s < 8; s++) {
    m[s] = wsf[MPART_F + s * NT + row];
    l[s] = wsf[LPART_F + s * NT + row];
  }
  float ms = m[0];
#pragma unroll
  for (int s = 1; s < 8; s++) ms = fmaxf(ms, m[s]);
  float denom = 0.f;
  float acc[4] = {0.f, 0.f, 0.f, 0.f};
#pragma unroll
  for (int s = 0; s < 8; s++) {
    float w = exp2f((m[s] - ms) * LOG2E);
    denom += w * l[s];
    const u16* pp = opart + ((size_t)s * NT + row) * 256 + cg * 4;
    uint2 v = *(const uint2*)pp;
    acc[0] += w * bf2f((u16)(v.x & 0xffff));
    acc[1] += w * bf2f((u16)(v.x >> 16));
    acc[2] += w * bf2f((u16)(v.y & 0xffff));
    acc[3] += w * bf2f((u16)(v.y >> 16));
  }
  float inv = 1.0f / denom;
  f32x4 r = {acc[0] * inv, acc[1] * inv, acc[2] * inv, acc[3] * inv};
  *(f32x4*)(out + (size_t)row * 256 + cg * 4) = r;
}

extern "C" void kernel_launch(void* const* d_in, const int* in_sizes, int n_in,
                              void* d_out, int out_size, void* d_ws, size_t ws_size,
                              hipStream_t stream) {
  const float* x1 = (const float*)d_in[0];
  const float* x2 = (const float*)d_in[1];
  const float* x3 = (const float*)d_in[2];
  const float* Wq = (const float*)d_in[3];
  const float* bq = (const float*)d_in[4];
  const float* Wk = (const float*)d_in[5];
  const float* bk = (const float*)d_in[6];
  const float* Wv = (const float*)d_in[7];
  const float* bv = (const float*)d_in[8];
  u16* wsu = (u16*)d_ws;
  float* wsf = (float*)d_ws;
  float* out = (float*)d_out;

  k_convert<<<dim3(3168), dim3(256), 0, stream>>>(x1, x2, x3, Wq, Wk, Wv, wsu);
  k_qkv<<<dim3(768), dim3(256), 0, stream>>>(wsu, bq, bk, bv);
  k_flash<<<dim3(512), dim3(256), 0, stream>>>(wsu, wsu + OPARTB, wsf);
  k_combine<<<dim3(2048), dim3(256), 0, stream>>>(wsu + OPARTB, wsf, out);
}